// Round 13
// baseline (64.703 us; speedup 1.0000x reference)
//
#include <hip/hip_runtime.h>

constexpr int kN = 4, kC = 19, kH = 512, kW = 512;
constexpr int kHW = kH * kW;                       // 2^18
constexpr int kS = 2048;      // NUM_SUPERPIXEL
constexpr int kSsm = 8192;    // NUM_SMALL
constexpr float kEps = 1e-8f;

constexpr int kNSC = kN * kS * kC;                 // need_mark domain (155,648)
constexpr int kPixBlocks = kN * kHW / 256;         // 4096 (exact)

// ---- workspace layout (bytes) ----
constexpr size_t OFF_AMAX = 0;                                   // u64[N*S*C] (value_bits<<32)|~pix
constexpr size_t SZ_AMAX  = (size_t)kN * kS * kC * 8;
constexpr size_t OFF_MULT = OFF_AMAX + SZ_AMAX;                  // u32[N*Ssm*C] multiplicity
constexpr size_t SZ_MULT  = (size_t)kN * kSsm * kC * 4;
constexpr size_t OFF_NM   = OFF_MULT + SZ_MULT;                  // u32[N*Ssm] needed-channel bits
constexpr size_t SZ_NM    = (size_t)kN * kSsm * 4;
constexpr size_t ZERO_BYTES = OFF_NM + SZ_NM;                    // zeroed region (16B-multiple)
constexpr size_t ZERO_CHUNKS = ZERO_BYTES / 16;
constexpr size_t OFF_TM   = ZERO_BYTES;                          // u32[N*S] target channel bitmask
constexpr size_t SZ_TM    = (size_t)kN * kS * 4;
constexpr size_t OFF_WK   = OFF_TM + SZ_TM;                      // u32[N*HW] packed (s<<19)|tm
constexpr size_t SZ_WK    = (size_t)kN * kHW * 4;
constexpr size_t OFF_PL   = OFF_WK + SZ_WK;                      // f32[kPixBlocks] loss partials
constexpr size_t SZ_PL    = (size_t)kPixBlocks * 4;
constexpr size_t OFF_PN   = OFF_PL + SZ_PL;                      // i32[kPixBlocks] nv partials
constexpr size_t SZ_PN    = (size_t)kPixBlocks * 4;
constexpr size_t WS_TOTAL = OFF_PN + SZ_PN;

// Fused: zero the accumulator region + build tmask.
__global__ void init_kernel(const float* __restrict__ targets,
                            unsigned* __restrict__ tmask,
                            ulong2* __restrict__ ws) {
    size_t gid = (size_t)blockIdx.x * blockDim.x + threadIdx.x;
    if (gid < ZERO_CHUNKS) ws[gid] = ulong2{0ULL, 0ULL};
    if (gid < (size_t)kN * kS) {
        const float* t = targets + gid * (kC + 1);
        unsigned m = 0;
#pragma unroll
        for (int c = 0; c < kC; ++c)
            if (t[c] > 0.f) m |= (1u << c);
        tmask[gid] = m;
    }
}

// R12: hoist weak's 3-deep dependent head chain (mask -> seg -> tmask
// gather) into a dedicated streaming kernel with nothing downstream —
// latency fully hidden by TLP. Packs (s<<19)|tm into one u32 per pixel
// (kHW=2^18, s<2^11, tm<2^19; 0 <=> dead). Weak then starts with a single
// coalesced 4B load.
__global__ void wkey_kernel(const unsigned char* __restrict__ mask,
                            const int* __restrict__ seg,
                            const unsigned* __restrict__ tmask,
                            unsigned* __restrict__ wkey) {
    int gid = blockIdx.x * blockDim.x + threadIdx.x;  // exact grid
    int n = gid >> 18;
    unsigned k = 0;
    if (mask[gid]) {
        int s = seg[gid];
        unsigned tm = tmask[n * kS + s];
        if (tm) k = ((unsigned)s << 19) | tm;
    }
    wkey[gid] = k;
}

// Weak branch (R10 structure): per-(segment,channel) lexicographic argmax
// via fire-and-forget u64 atomicMax of (float_bits(v)<<32)|~pixel.
// Two-pass softmax (sum only, no x[19] array), __ffs over live channels.
__global__ void weak_argmax_kernel(const float* __restrict__ logits,
                                   const unsigned* __restrict__ wkey,
                                   unsigned long long* __restrict__ amax) {
    int gid = blockIdx.x * blockDim.x + threadIdx.x;
    unsigned k = wkey[gid];
    if (!k) return;
    int n = gid >> 18;
    int p = gid & (kHW - 1);
    unsigned tm = k & 0x7FFFFu;
    int s = (int)(k >> 19);

    const float* base = logits + (size_t)n * kC * kHW + p;
    float sum = 0.f;
#pragma unroll
    for (int c = 0; c < kC; ++c)
        sum += __expf(base[(size_t)c * kHW]);
    float inv = 1.f / sum;

    unsigned long long lowbits = (unsigned int)(~(unsigned int)p);
    unsigned long long* dst = amax + ((size_t)n * kS + s) * kC;
    unsigned bits = tm;
    while (bits) {
        int c = __ffs(bits) - 1;
        bits &= bits - 1;
        float v = __expf(base[(size_t)c * kHW]) * inv;  // L1-hot reload
        unsigned long long key =
            ((unsigned long long)__float_as_uint(v) << 32) | lowbits;
        atomicMax(&dst[c], key);
    }
}

// For each live (n,s,c) pair: record needed-channel bit and multiplicity.
// (R10 summation-order swap: mult lets strong emit the final loss directly.)
__global__ void need_mark_kernel(const unsigned long long* __restrict__ amax,
                                 const unsigned* __restrict__ tmask,
                                 const int* __restrict__ small_w,
                                 unsigned* __restrict__ needmask,
                                 unsigned* __restrict__ mult) {
    int gid = blockIdx.x * blockDim.x + threadIdx.x;
    if (gid >= kNSC) return;
    int n = gid / (kS * kC);
    int rem = gid - n * (kS * kC);
    int s = rem / kC;
    int c = rem - s * kC;
    if (!((tmask[n * kS + s] >> c) & 1u)) return;
    unsigned long long packed = amax[gid];
    if (packed == 0ULL) return;  // empty segment (has_pixel == false)
    unsigned pix = ~(unsigned)(packed & 0xFFFFFFFFULL);
    int sel = small_w[(size_t)n * kHW + pix];
    atomicOr(&needmask[n * kSsm + sel], 1u << c);
    atomicAdd(&mult[((size_t)n * kSsm + sel) * kC + c], 1u);
}

// Strong branch (R10 structure, 1 pixel/thread): per masked pixel whose
// small superpixel is needed, softmax + mult-weighted nll, block-reduced
// to one (loss, nv) partial per block. No scattered atomics.
__global__ void strong_loss_kernel(const float* __restrict__ logits,
                                   const unsigned char* __restrict__ mask,
                                   const int* __restrict__ seg,
                                   const unsigned* __restrict__ needmask,
                                   const unsigned* __restrict__ mult,
                                   float* __restrict__ ploss,
                                   int* __restrict__ pnv) {
    __shared__ float sLoss[4];
    __shared__ int sNv[4];
    int gid = blockIdx.x * blockDim.x + threadIdx.x;  // exact grid
    float loss = 0.f;
    int nvv = 0;
    if (mask[gid]) {
        int n = gid >> 18;
        int p = gid & (kHW - 1);
        int ss = seg[gid];
        unsigned nm = needmask[n * kSsm + ss];
        if (nm) {
            const float* base = logits + (size_t)n * kC * kHW + p;
            float sum = 0.f;
#pragma unroll
            for (int c = 0; c < kC; ++c)
                sum += __expf(base[(size_t)c * kHW]);
            float inv = 1.f / sum;

            const unsigned* row = mult + ((size_t)n * kSsm + ss) * kC;
            unsigned bits = nm;
            while (bits) {
                int c = __ffs(bits) - 1;
                bits &= bits - 1;
                unsigned m = row[c];                            // L2-resident
                float v = __expf(base[(size_t)c * kHW]) * inv;  // L1-hot reload
                loss += (float)m * (-__logf(v + kEps));
                nvv += (int)m;
            }
        }
    }
    // all threads reach here (no early returns) — block reduction
#pragma unroll
    for (int off = 32; off > 0; off >>= 1) {
        loss += __shfl_down(loss, off);
        nvv += __shfl_down(nvv, off);
    }
    int wave = threadIdx.x >> 6;
    if ((threadIdx.x & 63) == 0) {
        sLoss[wave] = loss;
        sNv[wave] = nvv;
    }
    __syncthreads();
    if (threadIdx.x == 0) {
        ploss[blockIdx.x] = sLoss[0] + sLoss[1] + sLoss[2] + sLoss[3];
        pnv[blockIdx.x]   = sNv[0] + sNv[1] + sNv[2] + sNv[3];
    }
}

// Single-block reduction of the 4096 per-block partials + final divide.
__global__ void finalize_kernel(const float* __restrict__ ploss,
                                const int* __restrict__ pnv,
                                float* __restrict__ out) {
    __shared__ float sLoss[4];
    __shared__ int sNv[4];
    float lv = 0.f;
    int nvv = 0;
    for (int i = threadIdx.x; i < kPixBlocks; i += 256) {
        lv += ploss[i];
        nvv += pnv[i];
    }
#pragma unroll
    for (int off = 32; off > 0; off >>= 1) {
        lv += __shfl_down(lv, off);
        nvv += __shfl_down(nvv, off);
    }
    int wave = threadIdx.x >> 6;
    if ((threadIdx.x & 63) == 0) {
        sLoss[wave] = lv;
        sNv[wave] = nvv;
    }
    __syncthreads();
    if (threadIdx.x == 0) {
        float tl = sLoss[0] + sLoss[1] + sLoss[2] + sLoss[3];
        int tn = sNv[0] + sNv[1] + sNv[2] + sNv[3];
        out[0] = tl / (float)(1 + tn);
    }
}

extern "C" void kernel_launch(void* const* d_in, const int* in_sizes, int n_in,
                              void* d_out, int out_size, void* d_ws, size_t ws_size,
                              hipStream_t stream) {
    const float* inputs            = (const float*)d_in[0];
    const float* inputs_weak       = (const float*)d_in[1];
    const float* targets           = (const float*)d_in[2];
    const unsigned char* spmasks      = (const unsigned char*)d_in[3];
    const unsigned char* spmasks_weak = (const unsigned char*)d_in[4];
    // d_in[5] superpixels: unused by the reference
    const int* superpixels_weak    = (const int*)d_in[6];
    const int* superpixel_smalls   = (const int*)d_in[7];
    const int* spx_smalls_weak     = (const int*)d_in[8];
    float* out = (float*)d_out;

    unsigned long long* amax = (unsigned long long*)((char*)d_ws + OFF_AMAX);
    unsigned* mult           = (unsigned*)((char*)d_ws + OFF_MULT);
    unsigned* needmask       = (unsigned*)((char*)d_ws + OFF_NM);
    unsigned* tmask          = (unsigned*)((char*)d_ws + OFF_TM);
    unsigned* wkey           = (unsigned*)((char*)d_ws + OFF_WK);
    float* ploss             = (float*)((char*)d_ws + OFF_PL);
    int* pnv                 = (int*)((char*)d_ws + OFF_PN);

    int initThreads = (int)ZERO_CHUNKS;
    init_kernel<<<(initThreads + 255) / 256, 256, 0, stream>>>(targets, tmask,
                                                               (ulong2*)d_ws);
    wkey_kernel<<<kPixBlocks, 256, 0, stream>>>(spmasks_weak, superpixels_weak,
                                                tmask, wkey);
    weak_argmax_kernel<<<kPixBlocks, 256, 0, stream>>>(inputs_weak, wkey, amax);
    need_mark_kernel<<<(kNSC + 255) / 256, 256, 0, stream>>>(amax, tmask,
                                                             spx_smalls_weak,
                                                             needmask, mult);
    strong_loss_kernel<<<kPixBlocks, 256, 0, stream>>>(inputs, spmasks,
                                                       superpixel_smalls,
                                                       needmask, mult, ploss, pnv);
    finalize_kernel<<<1, 256, 0, stream>>>(ploss, pnv, out);
}